// Round 12
// baseline (562.394 us; speedup 1.0000x reference)
//
#include <hip/hip_runtime.h>

// Problem constants
#define S_TOK 4096
#define D_DIM 4096
#define O_DIM 4096
#define R_DIM 256
#define E_EXP 8
#define NTOK  8192   // B*S
#define KSPLIT 4

typedef __bf16 bf16x8 __attribute__((ext_vector_type(8)));
typedef float  f32x4  __attribute__((ext_vector_type(4)));

__device__ __forceinline__ unsigned short f2bf(float f) {
  unsigned int u = __float_as_uint(f);
  u += 0x7FFFu + ((u >> 16) & 1u);   // RNE (no NaN in data)
  return (unsigned short)(u >> 16);
}
__device__ __forceinline__ float bf2f(unsigned short h) {
  return __uint_as_float(((unsigned int)h) << 16);
}

__device__ __forceinline__ void gload_lds16(const unsigned short* g, unsigned short* l) {
  __builtin_amdgcn_global_load_lds((const __attribute__((address_space(1))) void*)g,
                                   (__attribute__((address_space(3))) void*)l, 16, 0, 0);
}

// Fused counted-wait + barrier as ONE volatile asm with memory clobber.
#define PIPE_FENCE(N)                                                        \
  do {                                                                       \
    asm volatile("s_waitcnt vmcnt(" #N ")\n\ts_barrier" ::: "memory");       \
    __builtin_amdgcn_sched_barrier(0);                                       \
  } while (0)

// ============ merged prologue: casts + transposes + token sort, one launch ============
__global__ void prologue(const float* __restrict__ x, const float* __restrict__ wb,
                         const float* __restrict__ la, const float* __restrict__ lb,
                         unsigned short* __restrict__ X16, unsigned short* __restrict__ W16,
                         unsigned short* __restrict__ A16t, unsigned short* __restrict__ B16t,
                         const int* __restrict__ tt, int* __restrict__ token_perm,
                         int* __restrict__ inv_perm, int* __restrict__ tile_e,
                         int* __restrict__ tile_j0, int* __restrict__ tile_jend,
                         int* __restrict__ ntiles_out) {
  __shared__ int sm[10256];
  const int b = blockIdx.x, t = threadIdx.x;
  if (b >= 40960) {
    int* ltt   = sm;
    int* lc    = sm + 4096;
    int* ssl   = sm + 6144;
    int* basee = sm + 10240;
    int* cnte  = sm + 10248;
    for (int s = t; s < S_TOK; s += 256) ltt[s] = tt[s];
    __syncthreads();
    int c[8] = {0,0,0,0,0,0,0,0};
    #pragma unroll
    for (int i = 0; i < 16; i++) { int e = ltt[t * 16 + i]; c[e]++; }
    #pragma unroll
    for (int e = 0; e < 8; e++) lc[t * 8 + e] = c[e];
    __syncthreads();
    if (t < 8) {
      int run = 0;
      for (int qq = 0; qq < 256; qq++) { int tmp = lc[qq * 8 + t]; lc[qq * 8 + t] = run; run += tmp; }
      cnte[t] = run;
    }
    __syncthreads();
    if (t == 0) { int tot = 0; for (int e = 0; e < 8; e++) { basee[e] = tot; tot += cnte[e]; } }
    __syncthreads();
    int off[8];
    #pragma unroll
    for (int e = 0; e < 8; e++) off[e] = basee[e] + lc[t * 8 + e];
    #pragma unroll
    for (int i = 0; i < 16; i++) { int s = t * 16 + i; int e = ltt[s]; ssl[off[e]++] = s; }
    __syncthreads();
    for (int j = t; j < NTOK; j += 256) {
      int row = ((j & 1) << 12) + ssl[j >> 1];
      token_perm[j] = row;
      inv_perm[row] = j;
    }
    if (t == 0) {
      int nt = 0;
      for (int e = 0; e < 8; e++) {
        int js = 2 * basee[e], je = js + 2 * cnte[e];
        for (int j0 = js; j0 < je; j0 += 128) {
          tile_e[nt] = e; tile_j0[nt] = j0;
          tile_jend[nt] = (je < j0 + 128) ? je : (j0 + 128);
          nt++;
        }
      }
      *ntiles_out = nt;
    }
    return;
  }
  if (b < 24576) {
    const float* in  = (b < 16384) ? x : wb;
    unsigned short* out = (b < 16384) ? X16 : W16;
    size_t g = (size_t)((b < 16384) ? b : (b - 16384)) * 256 + t;
    const float4* i4 = (const float4*)in;
    float4 a = i4[g * 2], c = i4[g * 2 + 1];
    union { unsigned short h[8]; int4 v; } u;
    u.h[0] = f2bf(a.x); u.h[1] = f2bf(a.y); u.h[2] = f2bf(a.z); u.h[3] = f2bf(a.w);
    u.h[4] = f2bf(c.x); u.h[5] = f2bf(c.y); u.h[6] = f2bf(c.z); u.h[7] = f2bf(c.w);
    ((int4*)out)[g] = u.v;
    return;
  }
  unsigned short (*tile)[33] = (unsigned short (*)[33])sm;
  const float* in; unsigned short* out; int P, Q, pt, qt, e;
  if (b < 32768) {
    int b2 = b - 24576; e = b2 >> 10; int rem = b2 & 1023;
    in = la; out = A16t; P = D_DIM; Q = R_DIM;
    pt = (rem >> 3) * 32; qt = (rem & 7) * 32;
  } else {
    int b3 = b - 32768; e = b3 >> 10; int rem = b3 & 1023;
    in = lb; out = B16t; P = R_DIM; Q = D_DIM;
    pt = (rem & 7) * 32; qt = (rem >> 3) * 32;
  }
  const float* ie = in + (size_t)e * P * Q;
  unsigned short* oe = out + (size_t)e * P * Q;
  int tx = t & 31, ty = t >> 5;
  #pragma unroll
  for (int i = 0; i < 32; i += 8) {
    int p = pt + ty + i, q = qt + tx;
    tile[ty + i][tx] = f2bf(ie[(size_t)p * Q + q]);
  }
  __syncthreads();
  #pragma unroll
  for (int i = 0; i < 32; i += 8) {
    int q = qt + ty + i, p = pt + tx;
    oe[(size_t)q * P + p] = tile[tx][ty + i];
  }
}

// ===================== 128x128 read-ahead dense GEMM, 2 blocks/CU =====================
// Faithful geometry-shrink of the R9/R11-verified skeleton: 4 waves (2x2, wave
// tile 64x64), BK=64 as 2 k-halves, LDS 64KB -> TWO blocks/CU (R11 had 128KB ->
// 1 block/CU; MfmaUtil 46 + VALU 19 = ~35% CU-idle at fences with nothing else
// to run). Same stage order, 2 loads/half, vmcnt(4) fences at ph1/ph3, 4->0 tail.
template<int FUSED>
__global__ __launch_bounds__(256, 2) void gemm128_dense(
    const unsigned short* __restrict__ A, const unsigned short* __restrict__ B,
    float* __restrict__ C, const unsigned short* __restrict__ lout,
    const int* __restrict__ invp) {
  __shared__ __align__(16) unsigned short ldsA[2][2][4096];  // [ring][khalf][128x32]
  __shared__ __align__(16) unsigned short ldsB[2][2][4096];
  // 2D XCD swizzle over the 64x32 tile grid: XCDs as 4x2 grid of 16x16 chunks
  int b = blockIdx.x;
  int xc = b & 7, q = b >> 3;
  const int bm = (xc >> 1) * 16 + (q >> 4);   // 0..63
  const int bn = (xc & 1) * 16 + (q & 15);    // 0..31
  const int tid = threadIdx.x, l = tid & 63, w = tid >> 6;
  const int wm = w >> 1, wn = w & 1;

  const unsigned short *srcA0, *srcA1, *srcB0, *srcB1;
  {
    int i0 = tid, r0 = i0 >> 2;
    int c0 = ((i0 & 3) * 16) ^ (((r0 >> 1) & 3) << 4);
    srcA0 = A + (size_t)(bm * 128 + r0) * 4096 + (c0 >> 1);
    srcB0 = B + (size_t)(bn * 128 + r0) * 4096 + (c0 >> 1);
    int i1 = 256 + tid, r1 = i1 >> 2;
    int c1 = ((i1 & 3) * 16) ^ (((r1 >> 1) & 3) << 4);
    srcA1 = A + (size_t)(bm * 128 + r1) * 4096 + (c1 >> 1);
    srcB1 = B + (size_t)(bn * 128 + r1) * 4096 + (c1 >> 1);
  }
  const int d0 = tid * 8;

  const int lane15 = l & 15, kb16 = (l >> 4) * 16;
  int offA[4], offB[4];
  #pragma unroll
  for (int m = 0; m < 4; m++) {
    int r = wm * 64 + m * 16 + lane15;
    offA[m] = r * 64 + (kb16 ^ (((r >> 1) & 3) << 4));
  }
  #pragma unroll
  for (int n = 0; n < 4; n++) {
    int r = wn * 64 + n * 16 + lane15;
    offB[n] = r * 64 + (kb16 ^ (((r >> 1) & 3) << 4));
  }

  f32x4 acc[4][4];
  #pragma unroll
  for (int m = 0; m < 4; m++)
    #pragma unroll
    for (int n = 0; n < 4; n++) acc[m][n] = (f32x4){0.f, 0.f, 0.f, 0.f};

  bf16x8 Ab0[2], Ab1[2], Bb0[4], Bb1[4];

#define STAGE_A(tt, kh) do { int _o = (tt) * 64 + (kh) * 32;                  \
    gload_lds16(srcA0 + _o, &ldsA[(tt) & 1][kh][d0]);                         \
    gload_lds16(srcA1 + _o, &ldsA[(tt) & 1][kh][d0 + 2048]); } while (0)
#define STAGE_B(tt, kh) do { int _o = (tt) * 64 + (kh) * 32;                  \
    gload_lds16(srcB0 + _o, &ldsB[(tt) & 1][kh][d0]);                         \
    gload_lds16(srcB1 + _o, &ldsB[(tt) & 1][kh][d0 + 2048]); } while (0)
#define RD_A(RING, QQ, KS, BUF) do {                                          \
    const char* _s = (const char*)&ldsA[RING][KS][0];                         \
    BUF[0] = *(const bf16x8*)(_s + offA[(QQ) * 2 + 0]);                       \
    BUF[1] = *(const bf16x8*)(_s + offA[(QQ) * 2 + 1]); } while (0)
#define RD_B(RING, KS, BUF) do {                                              \
    const char* _s = (const char*)&ldsB[RING][KS][0];                         \
    BUF[0] = *(const bf16x8*)(_s + offB[0]);                                  \
    BUF[1] = *(const bf16x8*)(_s + offB[1]);                                  \
    BUF[2] = *(const bf16x8*)(_s + offB[2]);                                  \
    BUF[3] = *(const bf16x8*)(_s + offB[3]); } while (0)
#define PRIO_MFMA(Q, AB, BB) do {                                             \
    __builtin_amdgcn_s_setprio(1);                                            \
    _Pragma("unroll")                                                         \
    for (int mm = 0; mm < 2; mm++)                                            \
      _Pragma("unroll")                                                       \
      for (int nn = 0; nn < 4; nn++)                                          \
        acc[(Q) * 2 + mm][nn] = __builtin_amdgcn_mfma_f32_16x16x32_bf16(      \
            AB[mm], BB[nn], acc[(Q) * 2 + mm][nn], 0, 0, 0);                  \
    __builtin_amdgcn_s_setprio(0); } while (0)

  // prologue: A0k0,B0k0,A0k1,B0k1,A1k0,B1k0 (12 loads); vmcnt(4) -> oldest 8 landed
  STAGE_A(0, 0); STAGE_B(0, 0); STAGE_A(0, 1); STAGE_B(0, 1);
  STAGE_A(1, 0); STAGE_B(1, 0);
  PIPE_FENCE(4);
  RD_B(0, 0, Bb0); RD_A(0, 0, 0, Ab0);

  // steady: tiles 0..61 (fences only at ph1/ph3)
  #pragma unroll 1
  for (int t = 0; t < 62; ++t) {
    const int r = t & 1, nr = r ^ 1;
    RD_A(r, 1, 0, Ab1); STAGE_A(t + 1, 1);
    PRIO_MFMA(0, Ab0, Bb0);
    RD_B(r, 1, Bb1); RD_A(r, 0, 1, Ab0); STAGE_B(t + 1, 1);
    PRIO_MFMA(1, Ab1, Bb0);
    PIPE_FENCE(4);
    RD_A(r, 1, 1, Ab1); STAGE_A(t + 2, 0);
    PRIO_MFMA(0, Ab0, Bb1);
    RD_B(nr, 0, Bb0); RD_A(nr, 0, 0, Ab0); STAGE_B(t + 2, 0);
    PRIO_MFMA(1, Ab1, Bb1);
    PIPE_FENCE(4);
  }
  // tile 62 (r=0): stages only k1(63); F3 drains to 0
  RD_A(0, 1, 0, Ab1); STAGE_A(63, 1); PRIO_MFMA(0, Ab0, Bb0);
  RD_B(0, 1, Bb1); RD_A(0, 0, 1, Ab0); STAGE_B(63, 1); PRIO_MFMA(1, Ab1, Bb0);
  PIPE_FENCE(4);
  RD_A(0, 1, 1, Ab1); PRIO_MFMA(0, Ab0, Bb1);
  RD_B(1, 0, Bb0); RD_A(1, 0, 0, Ab0); PRIO_MFMA(1, Ab1, Bb1);
  PIPE_FENCE(0);
  // tile 63 (r=1): no stages, no fences
  RD_A(1, 1, 0, Ab1); PRIO_MFMA(0, Ab0, Bb0);
  RD_B(1, 1, Bb1); RD_A(1, 0, 1, Ab0); PRIO_MFMA(1, Ab1, Bb0);
  RD_A(1, 1, 1, Ab1); PRIO_MFMA(0, Ab0, Bb1);
  PRIO_MFMA(1, Ab1, Bb1);

#undef STAGE_A
#undef STAGE_B
#undef RD_A
#undef RD_B
#undef PRIO_MFMA

  const int rowbase = bm * 128 + wm * 64;
  const int colbase = bn * 128 + wn * 64;
  #pragma unroll
  for (int m = 0; m < 4; m++)
    #pragma unroll
    for (int v = 0; v < 4; v++) {
      int rrow = rowbase + m * 16 + (l >> 4) * 4 + v;
      float lv0 = 0.f, lv1 = 0.f, lv2 = 0.f, lv3 = 0.f;
      if (FUSED) {
        int jr = invp[rrow];
        const unsigned short* lr = lout + (size_t)jr * O_DIM + colbase + lane15;
        lv0 = bf2f(lr[0]); lv1 = bf2f(lr[16]); lv2 = bf2f(lr[32]); lv3 = bf2f(lr[48]);
      }
      size_t base = (size_t)rrow * O_DIM + colbase + lane15;
      C[base]      = acc[m][0][v] + lv0;
      C[base + 16] = acc[m][1][v] + lv1;
      C[base + 32] = acc[m][2][v] + lv2;
      C[base + 48] = acc[m][3][v] + lv3;
    }
}

// ======= pipelined 128x128 LoRA GEMM (unchanged, passed R10/R11) =======
template<int MODE>
__global__ __launch_bounds__(256, 2) void gemm_nt(
    const unsigned short* __restrict__ Aop, const unsigned short* __restrict__ Bop,
    unsigned short* __restrict__ outU,
    const int* __restrict__ perm, const int* __restrict__ tile_e,
    const int* __restrict__ tile_j0, const int* __restrict__ tile_jend,
    const int* __restrict__ ntiles, int K) {
  int bm = blockIdx.x, bn = blockIdx.y;
  if (bm >= *ntiles) return;
  int e = tile_e[bm], j0 = tile_j0[bm], jend = tile_jend[bm];
  const int kc = (MODE == 1) ? blockIdx.z : 0;
  const int t = threadIdx.x, l = t & 63, w = t >> 6;
  const int wm = w >> 1, wn = w & 1;
  __shared__ __align__(16) unsigned short ldsA[4][4096];
  __shared__ __align__(16) unsigned short ldsB[4][4096];

  const unsigned short *sA0, *sA1, *sB0, *sB1;
  {
    int i0 = t, r0 = i0 >> 2;
    int c0 = ((i0 & 3) * 16) ^ (((r0 >> 1) & 3) << 4);
    int i1 = 256 + t, r1 = i1 >> 2;
    int c1 = ((i1 & 3) * 16) ^ (((r1 >> 1) & 3) << 4);
    int ja = j0 + r0; if (ja > jend - 1) ja = jend - 1;
    int jb = j0 + r1; if (jb > jend - 1) jb = jend - 1;
    int g0 = (MODE == 1) ? perm[ja] : ja;
    int g1 = (MODE == 1) ? perm[jb] : jb;
    sA0 = Aop + (size_t)g0 * K + kc * 1024 + (c0 >> 1);
    sA1 = Aop + (size_t)g1 * K + kc * 1024 + (c1 >> 1);
    const unsigned short* bp = Bop + ((MODE == 1) ? (size_t)e * R_DIM * D_DIM
                                                  : (size_t)e * O_DIM * R_DIM);
    sB0 = bp + (size_t)(bn * 128 + r0) * K + kc * 1024 + (c0 >> 1);
    sB1 = bp + (size_t)(bn * 128 + r1) * K + kc * 1024 + (c1 >> 1);
  }
  const int d0 = t * 8;

  const int lane15 = l & 15, kb16 = (l >> 4) * 16;
  int offA[4], offB[4];
  #pragma unroll
  for (int m = 0; m < 4; m++) {
    int r = wm * 64 + m * 16 + lane15;
    offA[m] = r * 64 + (kb16 ^ (((r >> 1) & 3) << 4));
  }
  #pragma unroll
  for (int n = 0; n < 4; n++) {
    int r = wn * 64 + n * 16 + lane15;
    offB[n] = r * 64 + (kb16 ^ (((r >> 1) & 3) << 4));
  }

  f32x4 acc[4][4];
  #pragma unroll
  for (int m = 0; m < 4; m++)
    #pragma unroll
    for (int n = 0; n < 4; n++) acc[m][n] = (f32x4){0.f, 0.f, 0.f, 0.f};

  auto stage = [&](int tt) {
    const int ring = tt & 3;
    const int go = tt * 32;
    gload_lds16(sA0 + go, &ldsA[ring][d0]);
    gload_lds16(sA1 + go, &ldsA[ring][d0 + 2048]);
    gload_lds16(sB0 + go, &ldsB[ring][d0]);
    gload_lds16(sB1 + go, &ldsB[ring][d0 + 2048]);
  };

  auto body = [&](int ring) {
    const char* bA = (const char*)&ldsA[ring][0];
    const char* bB = (const char*)&ldsB[ring][0];
    bf16x8 a[4], bb[4];
    #pragma unroll
    for (int m = 0; m < 4; m++) a[m] = *(const bf16x8*)(bA + offA[m]);
    #pragma unroll
    for (int n = 0; n < 4; n++) bb[n] = *(const bf16x8*)(bB + offB[n]);
    __builtin_amdgcn_s_setprio(1);
    #pragma unroll
    for (int m = 0; m < 4; m++)
      #pragma unroll
      for (int n = 0; n < 4; n++)
        acc[m][n] = __builtin_amdgcn_mfma_f32_16x16x32_bf16(a[m], bb[n], acc[m][n], 0, 0, 0);
    __builtin_amdgcn_s_setprio(0);
  };

  const int nk = (MODE == 1) ? 32 : (K / 32);
  stage(0); stage(1); stage(2);
  PIPE_FENCE(8);
  #pragma unroll 1
  for (int kt = 0; kt < nk - 3; ++kt) {
    stage(kt + 3);
    body(kt & 3);
    PIPE_FENCE(8);
  }
  body((nk - 3) & 3);
  PIPE_FENCE(4);
  body((nk - 2) & 3);
  PIPE_FENCE(0);
  body((nk - 1) & 3);

  const int rowbase = j0 + wm * 64;
  const int colbase = bn * 128 + wn * 64;
  #pragma unroll
  for (int m = 0; m < 4; m++) {
    #pragma unroll
    for (int n = 0; n < 4; n++) {
      #pragma unroll
      for (int v = 0; v < 4; v++) {
        int r = rowbase + m * 16 + (l >> 4) * 4 + v;
        int cc = colbase + n * 16 + lane15;
        if (r < jend) {
          if (MODE == 1) {
            outU[(size_t)kc * (NTOK * R_DIM) + (size_t)r * R_DIM + cc] = f2bf(acc[m][n][v]);
          } else {
            outU[(size_t)r * O_DIM + cc] = f2bf(2.0f * acc[m][n][v]);
          }
        }
      }
    }
  }
}

// ---------------- reduce bf16 split-K partials -> bf16 H16s ----------------
__global__ void reduce_h(const unsigned short* __restrict__ hp, unsigned short* __restrict__ h16) {
  size_t g = (size_t)blockIdx.x * 256 + threadIdx.x;
  float s[8] = {0,0,0,0,0,0,0,0};
  #pragma unroll
  for (int c = 0; c < KSPLIT; c++) {
    int4 v = ((const int4*)hp)[g + (size_t)c * (NTOK * R_DIM / 8)];
    const unsigned short* us = (const unsigned short*)&v;
    #pragma unroll
    for (int i = 0; i < 8; i++) s[i] += bf2f(us[i]);
  }
  union { unsigned short h[8]; int4 v; } u;
  #pragma unroll
  for (int i = 0; i < 8; i++) u.h[i] = f2bf(s[i]);
  ((int4*)h16)[g] = u.v;
}

// ---------------- workspace layout (bytes) ----------------
#define X16_OFF   ((size_t)0)             // 67108864
#define W16_OFF   ((size_t)67108864)      // 33554432
#define A16T_OFF  ((size_t)100663296)     // 16777216
#define B16T_OFF  ((size_t)117440512)     // 16777216
#define H16S_OFF  ((size_t)134217728)     // 4194304
#define PERM_OFF  ((size_t)138412032)     // 32768
#define INVP_OFF  ((size_t)138444800)     // 32768
#define TILEE_OFF ((size_t)138477568)     // 512
#define TILEJ0_OFF ((size_t)138478080)
#define TILEJE_OFF ((size_t)138478592)
#define NT_OFF    ((size_t)138479104)
#define HP16_OFF  ((size_t)138479616)     // 16777216
#define LOUT_OFF  ((size_t)155256832)     // 67108864

extern "C" void kernel_launch(void* const* d_in, const int* in_sizes, int n_in,
                              void* d_out, int out_size, void* d_ws, size_t ws_size,
                              hipStream_t stream) {
  const float* x  = (const float*)d_in[0];
  const float* wb = (const float*)d_in[1];
  const float* la = (const float*)d_in[2];
  const float* lb = (const float*)d_in[3];
  const int* tok  = (const int*)d_in[4];
  float* out = (float*)d_out;

  char* ws = (char*)d_ws;
  unsigned short* X16  = (unsigned short*)(ws + X16_OFF);
  unsigned short* W16  = (unsigned short*)(ws + W16_OFF);
  unsigned short* A16t = (unsigned short*)(ws + A16T_OFF);
  unsigned short* B16t = (unsigned short*)(ws + B16T_OFF);
  unsigned short* H16s = (unsigned short*)(ws + H16S_OFF);
  unsigned short* HP16 = (unsigned short*)(ws + HP16_OFF);
  unsigned short* LOUT = (unsigned short*)(ws + LOUT_OFF);
  int* perm  = (int*)(ws + PERM_OFF);
  int* invp  = (int*)(ws + INVP_OFF);
  int* tl_e  = (int*)(ws + TILEE_OFF);
  int* tl_j0 = (int*)(ws + TILEJ0_OFF);
  int* tl_je = (int*)(ws + TILEJE_OFF);
  int* nt    = (int*)(ws + NT_OFF);

  prologue<<<40961, 256, 0, stream>>>(x, wb, la, lb, X16, W16, A16t, B16t,
                                      tok, perm, invp, tl_e, tl_j0, tl_je, nt);

  gemm_nt<1><<<dim3(71, 2, KSPLIT), 256, 0, stream>>>(X16, A16t, HP16,
                                                      perm, tl_e, tl_j0, tl_je, nt, D_DIM);
  reduce_h<<<1024, 256, 0, stream>>>(HP16, H16s);
  gemm_nt<3><<<dim3(71, 32), 256, 0, stream>>>(H16s, B16t, LOUT,
                                               perm, tl_e, tl_j0, tl_je, nt, R_DIM);
  gemm128_dense<1><<<2048, 256, 0, stream>>>(X16, W16, out, LOUT, invp);
}

// Round 13
// 528.115 us; speedup vs baseline: 1.0649x; 1.0649x over previous
//
#include <hip/hip_runtime.h>

// Problem constants
#define S_TOK 4096
#define D_DIM 4096
#define O_DIM 4096
#define R_DIM 256
#define E_EXP 8
#define NTOK  8192   // B*S
#define KSPLIT 4

typedef __bf16 bf16x8 __attribute__((ext_vector_type(8)));
typedef float  f32x4  __attribute__((ext_vector_type(4)));

__device__ __forceinline__ unsigned short f2bf(float f) {
  unsigned int u = __float_as_uint(f);
  u += 0x7FFFu + ((u >> 16) & 1u);   // RNE (no NaN in data)
  return (unsigned short)(u >> 16);
}
__device__ __forceinline__ float bf2f(unsigned short h) {
  return __uint_as_float(((unsigned int)h) << 16);
}

__device__ __forceinline__ void gload_lds16(const unsigned short* g, unsigned short* l) {
  __builtin_amdgcn_global_load_lds((const __attribute__((address_space(1))) void*)g,
                                   (__attribute__((address_space(3))) void*)l, 16, 0, 0);
}

#define PIPE_FENCE(N)                                                        \
  do {                                                                       \
    asm volatile("s_waitcnt vmcnt(" #N ")\n\ts_barrier" ::: "memory");       \
    __builtin_amdgcn_sched_barrier(0);                                       \
  } while (0)
#define BARX                                                                 \
  do {                                                                       \
    asm volatile("s_barrier" ::: "memory");                                  \
    __builtin_amdgcn_sched_barrier(0);                                       \
  } while (0)

// ============ merged prologue: casts + transposes + token sort (R11, passed) ============
__global__ void prologue(const float* __restrict__ x, const float* __restrict__ wb,
                         const float* __restrict__ la, const float* __restrict__ lb,
                         unsigned short* __restrict__ X16, unsigned short* __restrict__ W16,
                         unsigned short* __restrict__ A16t, unsigned short* __restrict__ B16t,
                         const int* __restrict__ tt, int* __restrict__ token_perm,
                         int* __restrict__ inv_perm, int* __restrict__ tile_e,
                         int* __restrict__ tile_j0, int* __restrict__ tile_jend,
                         int* __restrict__ ntiles_out) {
  __shared__ int sm[10256];
  const int b = blockIdx.x, t = threadIdx.x;
  if (b >= 40960) {
    int* ltt   = sm;
    int* lc    = sm + 4096;
    int* ssl   = sm + 6144;
    int* basee = sm + 10240;
    int* cnte  = sm + 10248;
    for (int s = t; s < S_TOK; s += 256) ltt[s] = tt[s];
    __syncthreads();
    int c[8] = {0,0,0,0,0,0,0,0};
    #pragma unroll
    for (int i = 0; i < 16; i++) { int e = ltt[t * 16 + i]; c[e]++; }
    #pragma unroll
    for (int e = 0; e < 8; e++) lc[t * 8 + e] = c[e];
    __syncthreads();
    if (t < 8) {
      int run = 0;
      for (int qq = 0; qq < 256; qq++) { int tmp = lc[qq * 8 + t]; lc[qq * 8 + t] = run; run += tmp; }
      cnte[t] = run;
    }
    __syncthreads();
    if (t == 0) { int tot = 0; for (int e = 0; e < 8; e++) { basee[e] = tot; tot += cnte[e]; } }
    __syncthreads();
    int off[8];
    #pragma unroll
    for (int e = 0; e < 8; e++) off[e] = basee[e] + lc[t * 8 + e];
    #pragma unroll
    for (int i = 0; i < 16; i++) { int s = t * 16 + i; int e = ltt[s]; ssl[off[e]++] = s; }
    __syncthreads();
    for (int j = t; j < NTOK; j += 256) {
      int row = ((j & 1) << 12) + ssl[j >> 1];
      token_perm[j] = row;
      inv_perm[row] = j;
    }
    if (t == 0) {
      int nt = 0;
      for (int e = 0; e < 8; e++) {
        int js = 2 * basee[e], je = js + 2 * cnte[e];
        for (int j0 = js; j0 < je; j0 += 128) {
          tile_e[nt] = e; tile_j0[nt] = j0;
          tile_jend[nt] = (je < j0 + 128) ? je : (j0 + 128);
          nt++;
        }
      }
      *ntiles_out = nt;
    }
    return;
  }
  if (b < 24576) {
    const float* in  = (b < 16384) ? x : wb;
    unsigned short* out = (b < 16384) ? X16 : W16;
    size_t g = (size_t)((b < 16384) ? b : (b - 16384)) * 256 + t;
    const float4* i4 = (const float4*)in;
    float4 a = i4[g * 2], c = i4[g * 2 + 1];
    union { unsigned short h[8]; int4 v; } u;
    u.h[0] = f2bf(a.x); u.h[1] = f2bf(a.y); u.h[2] = f2bf(a.z); u.h[3] = f2bf(a.w);
    u.h[4] = f2bf(c.x); u.h[5] = f2bf(c.y); u.h[6] = f2bf(c.z); u.h[7] = f2bf(c.w);
    ((int4*)out)[g] = u.v;
    return;
  }
  unsigned short (*tile)[33] = (unsigned short (*)[33])sm;
  const float* in; unsigned short* out; int P, Q, pt, qt, e;
  if (b < 32768) {
    int b2 = b - 24576; e = b2 >> 10; int rem = b2 & 1023;
    in = la; out = A16t; P = D_DIM; Q = R_DIM;
    pt = (rem >> 3) * 32; qt = (rem & 7) * 32;
  } else {
    int b3 = b - 32768; e = b3 >> 10; int rem = b3 & 1023;
    in = lb; out = B16t; P = R_DIM; Q = D_DIM;
    pt = (rem & 7) * 32; qt = (rem >> 3) * 32;
  }
  const float* ie = in + (size_t)e * P * Q;
  unsigned short* oe = out + (size_t)e * P * Q;
  int tx = t & 31, ty = t >> 5;
  #pragma unroll
  for (int i = 0; i < 32; i += 8) {
    int p = pt + ty + i, q = qt + tx;
    tile[ty + i][tx] = f2bf(ie[(size_t)p * Q + q]);
  }
  __syncthreads();
  #pragma unroll
  for (int i = 0; i < 32; i += 8) {
    int q = qt + ty + i, p = pt + tx;
    oe[(size_t)q * P + p] = tile[tx][ty + i];
  }
}

// ===================== 256x256 quadrant-phase dense GEMM =====================
// BK=64, NKT=64. 8 waves (2Mx4N), wave tile 128x64. Phase = C-quadrant (qm,qn)
// x full K=64: 12 ds_read -> 16 MFMA.
// INTERLEAVED halves: A-half q = rows {wm*128+q*64..+63 : wm} stored as 128 LDS
// rows (u<64 -> wm0, u>=64 -> wm1); B-half q = cols {wn*64+q*32..+31 : wn} as
// 128 LDS rows (u>>5 = wn). Phase (qm,qn) reads ONLY A-half qm + B-half qn ->
// last reader of h0 halves is p1/p2 -> staging t+2's h0 at p2/p3 is WAR-legal.
// Stage schedule: p0:(t+1)Ah1  p1:(t+1)Bh1  p2:(t+2)Ah0  p3:(t+2)Bh0.
// Fences (2/K-tile): p0-trail vmcnt(6) [lands (t)Bh1, issued 3 phases prior];
// p3-trail vmcnt(8) [lands (t+1)Ah0/Bh0, issued 4-5 phases prior]. All stage->
// need leads >= 3 phases (~1200+ cyc > HBM latency) -- R8-R11's fences blocked
// on just-issued loads (1-phase lead), the measured ~2000 cyc/K-tile overhead.
// Rows are 128B; swizzle byte ^= (u&7)<<4 (inverse-swizzled global source).
// Prologue: 6 halves + FENCE(8). Tail: t62 fences 6,-,-,4; t63 fences 0,-,-,-.
template<int FUSED>
__global__ __launch_bounds__(512, 2) void gemm256_q(
    const unsigned short* __restrict__ A, const unsigned short* __restrict__ B,
    float* __restrict__ C, const unsigned short* __restrict__ lout,
    const int* __restrict__ invp) {
  __shared__ __align__(16) unsigned short ldsA[2][2][8192];  // [ring][half][128u x 64k]
  __shared__ __align__(16) unsigned short ldsB[2][2][8192];
  int b = blockIdx.x;
  int xc = b & 7, q = b >> 3;
  const int bm = (xc >> 1) * 8 + (q >> 3);   // 0..31
  const int bn = (xc & 1) * 8 + (q & 7);     // 0..15
  const int tid = threadIdx.x, l = tid & 63, w = tid >> 6;
  const int wm = w >> 2, wn = w & 3;

  // staging sources (inverse-swizzled): chunk ck in {0,1}: u = ck*64 + (tid>>3),
  // slot j = tid&7 holds k-bytes (j*16)^((u&7)<<4). A: global row = brA(u)+h*64,
  // brA = u + (u&64). B: global col = brB(u)+h*32, brB = (u>>5)*64 + (u&31).
  const int u0 = tid >> 3, j0s = tid & 7;
  const int ksw = ((j0s ^ (u0 & 7)) * 8);
  const unsigned short* srcA0 = A + (size_t)(bm * 256 + u0) * 4096 + ksw;
  const unsigned short* srcA1 = A + (size_t)(bm * 256 + 128 + u0) * 4096 + ksw;
  const int brB0 = ((u0 >> 5) << 6) + (u0 & 31);
  const int brB1 = (((64 + u0) >> 5) << 6) + (u0 & 31);
  const unsigned short* srcB0 = B + (size_t)(bn * 256 + brB0) * 4096 + ksw;
  const unsigned short* srcB1 = B + (size_t)(bn * 256 + brB1) * 4096 + ksw;

  // ds_read byte-offsets (within a 16KB half; kk=1 -> ^64)
  const int lane15 = l & 15, kbase = (l >> 4) * 16;
  const int lsw = (lane15 & 7) << 4;
  int offA[4], offB[2];
  #pragma unroll
  for (int j = 0; j < 4; j++) {
    int u = wm * 64 + j * 16 + lane15;
    offA[j] = u * 128 + (kbase ^ lsw);
  }
  #pragma unroll
  for (int i = 0; i < 2; i++) {
    int u = wn * 32 + i * 16 + lane15;
    offB[i] = u * 128 + (kbase ^ lsw);
  }

  f32x4 acc[8][4];
  #pragma unroll
  for (int m = 0; m < 8; m++)
    #pragma unroll
    for (int n = 0; n < 4; n++) acc[m][n] = (f32x4){0.f, 0.f, 0.f, 0.f};

#define STAGE_A(TT, H) do {                                                   \
    gload_lds16(srcA0 + (size_t)(H) * 262144 + (TT) * 64,                     \
                &ldsA[(TT) & 1][H][tid * 8]);                                 \
    gload_lds16(srcA1 + (size_t)(H) * 262144 + (TT) * 64,                     \
                &ldsA[(TT) & 1][H][4096 + tid * 8]); } while (0)
#define STAGE_B(TT, H) do {                                                   \
    gload_lds16(srcB0 + (size_t)(H) * 131072 + (TT) * 64,                     \
                &ldsB[(TT) & 1][H][tid * 8]);                                 \
    gload_lds16(srcB1 + (size_t)(H) * 131072 + (TT) * 64,                     \
                &ldsB[(TT) & 1][H][4096 + tid * 8]); } while (0)
#define NOSTAGE do {} while (0)

#define PH(RING, QM, QN, STAGE_STMT, TRAILER) do {                            \
    const char* _a = (const char*)&ldsA[RING][QM][0];                         \
    const char* _b = (const char*)&ldsB[RING][QN][0];                         \
    bf16x8 a0_[4], a1_[4], b0_[2], b1_[2];                                    \
    _Pragma("unroll")                                                         \
    for (int j = 0; j < 4; j++) {                                             \
      a0_[j] = *(const bf16x8*)(_a + offA[j]);                                \
      a1_[j] = *(const bf16x8*)(_a + (offA[j] ^ 64));                         \
    }                                                                         \
    _Pragma("unroll")                                                         \
    for (int i = 0; i < 2; i++) {                                             \
      b0_[i] = *(const bf16x8*)(_b + offB[i]);                                \
      b1_[i] = *(const bf16x8*)(_b + (offB[i] ^ 64));                         \
    }                                                                         \
    STAGE_STMT;                                                               \
    asm volatile("s_barrier\n\ts_waitcnt lgkmcnt(0)" ::: "memory");           \
    __builtin_amdgcn_sched_barrier(0);                                        \
    __builtin_amdgcn_s_setprio(1);                                            \
    _Pragma("unroll")                                                         \
    for (int j = 0; j < 4; j++)                                               \
      _Pragma("unroll")                                                       \
      for (int i = 0; i < 2; i++) {                                           \
        acc[(QM) * 4 + j][(QN) * 2 + i] = __builtin_amdgcn_mfma_f32_16x16x32_bf16( \
            a0_[j], b0_[i], acc[(QM) * 4 + j][(QN) * 2 + i], 0, 0, 0);        \
        acc[(QM) * 4 + j][(QN) * 2 + i] = __builtin_amdgcn_mfma_f32_16x16x32_bf16( \
            a1_[j], b1_[i], acc[(QM) * 4 + j][(QN) * 2 + i], 0, 0, 0);        \
      }                                                                       \
    __builtin_amdgcn_s_setprio(0);                                            \
    TRAILER;                                                                  \
  } while (0)

  // prologue: (0)Ah0,(0)Bh0,(0)Ah1,(0)Bh1,(1)Ah0,(1)Bh0 = 12 loads; FENCE(8)
  // -> oldest 4 loads landed = (0)Ah0,(0)Bh0 (needed at t0 p0); rest covered
  // by t0's p0-trail vmcnt(6).
  STAGE_A(0, 0); STAGE_B(0, 0); STAGE_A(0, 1); STAGE_B(0, 1);
  STAGE_A(1, 0); STAGE_B(1, 0);
  PIPE_FENCE(8);

  // steady: tiles 0..61
  #pragma unroll 1
  for (int t = 0; t < 62; ++t) {
    const int r = t & 1;
    PH(r, 0, 0, STAGE_A(t + 1, 1), PIPE_FENCE(6));
    PH(r, 0, 1, STAGE_B(t + 1, 1), BARX);
    PH(r, 1, 0, STAGE_A(t + 2, 0), BARX);
    PH(r, 1, 1, STAGE_B(t + 2, 0), PIPE_FENCE(8));
  }
  // tile 62 (ring 0): stages only (63)Ah1,(63)Bh1
  PH(0, 0, 0, STAGE_A(63, 1), PIPE_FENCE(6));
  PH(0, 0, 1, STAGE_B(63, 1), BARX);
  PH(0, 1, 0, NOSTAGE, BARX);
  PH(0, 1, 1, NOSTAGE, PIPE_FENCE(4));   // lands (63)Ah0,(63)Bh0
  // tile 63 (ring 1): p0-trail vmcnt(0) lands (63)Ah1,(63)Bh1
  PH(1, 0, 0, NOSTAGE, PIPE_FENCE(0));
  PH(1, 0, 1, NOSTAGE, BARX);
  PH(1, 1, 0, NOSTAGE, BARX);
  PH(1, 1, 1, NOSTAGE, NOSTAGE);

#undef STAGE_A
#undef STAGE_B
#undef NOSTAGE
#undef PH

  const int rowbase = bm * 256 + wm * 128;
  const int colbase = bn * 256 + wn * 64;
  #pragma unroll
  for (int m = 0; m < 8; m++)
    #pragma unroll
    for (int v = 0; v < 4; v++) {
      int rrow = rowbase + m * 16 + (l >> 4) * 4 + v;
      float lv0 = 0.f, lv1 = 0.f, lv2 = 0.f, lv3 = 0.f;
      if (FUSED) {
        int jr = invp[rrow];
        const unsigned short* lr = lout + (size_t)jr * O_DIM + colbase + lane15;
        lv0 = bf2f(lr[0]); lv1 = bf2f(lr[16]); lv2 = bf2f(lr[32]); lv3 = bf2f(lr[48]);
      }
      size_t base = (size_t)rrow * O_DIM + colbase + lane15;
      C[base]      = acc[m][0][v] + lv0;
      C[base + 16] = acc[m][1][v] + lv1;
      C[base + 32] = acc[m][2][v] + lv2;
      C[base + 48] = acc[m][3][v] + lv3;
    }
}

// ======= pipelined 128x128 LoRA GEMM (unchanged, passed R10/R11) =======
template<int MODE>
__global__ __launch_bounds__(256, 2) void gemm_nt(
    const unsigned short* __restrict__ Aop, const unsigned short* __restrict__ Bop,
    unsigned short* __restrict__ outU,
    const int* __restrict__ perm, const int* __restrict__ tile_e,
    const int* __restrict__ tile_j0, const int* __restrict__ tile_jend,
    const int* __restrict__ ntiles, int K) {
  int bm = blockIdx.x, bn = blockIdx.y;
  if (bm >= *ntiles) return;
  int e = tile_e[bm], j0 = tile_j0[bm], jend = tile_jend[bm];
  const int kc = (MODE == 1) ? blockIdx.z : 0;
  const int t = threadIdx.x, l = t & 63, w = t >> 6;
  const int wm = w >> 1, wn = w & 1;
  __shared__ __align__(16) unsigned short ldsA[4][4096];
  __shared__ __align__(16) unsigned short ldsB[4][4096];

  const unsigned short *sA0, *sA1, *sB0, *sB1;
  {
    int i0 = t, r0 = i0 >> 2;
    int c0 = ((i0 & 3) * 16) ^ (((r0 >> 1) & 3) << 4);
    int i1 = 256 + t, r1 = i1 >> 2;
    int c1 = ((i1 & 3) * 16) ^ (((r1 >> 1) & 3) << 4);
    int ja = j0 + r0; if (ja > jend - 1) ja = jend - 1;
    int jb = j0 + r1; if (jb > jend - 1) jb = jend - 1;
    int g0 = (MODE == 1) ? perm[ja] : ja;
    int g1 = (MODE == 1) ? perm[jb] : jb;
    sA0 = Aop + (size_t)g0 * K + kc * 1024 + (c0 >> 1);
    sA1 = Aop + (size_t)g1 * K + kc * 1024 + (c1 >> 1);
    const unsigned short* bp = Bop + ((MODE == 1) ? (size_t)e * R_DIM * D_DIM
                                                  : (size_t)e * O_DIM * R_DIM);
    sB0 = bp + (size_t)(bn * 128 + r0) * K + kc * 1024 + (c0 >> 1);
    sB1 = bp + (size_t)(bn * 128 + r1) * K + kc * 1024 + (c1 >> 1);
  }
  const int d0 = t * 8;

  const int lane15 = l & 15, kb16 = (l >> 4) * 16;
  int offA[4], offB[4];
  #pragma unroll
  for (int m = 0; m < 4; m++) {
    int r = wm * 64 + m * 16 + lane15;
    offA[m] = r * 64 + (kb16 ^ (((r >> 1) & 3) << 4));
  }
  #pragma unroll
  for (int n = 0; n < 4; n++) {
    int r = wn * 64 + n * 16 + lane15;
    offB[n] = r * 64 + (kb16 ^ (((r >> 1) & 3) << 4));
  }

  f32x4 acc[4][4];
  #pragma unroll
  for (int m = 0; m < 4; m++)
    #pragma unroll
    for (int n = 0; n < 4; n++) acc[m][n] = (f32x4){0.f, 0.f, 0.f, 0.f};

  auto stage = [&](int tt) {
    const int ring = tt & 3;
    const int go = tt * 32;
    gload_lds16(sA0 + go, &ldsA[ring][d0]);
    gload_lds16(sA1 + go, &ldsA[ring][d0 + 2048]);
    gload_lds16(sB0 + go, &ldsB[ring][d0]);
    gload_lds16(sB1 + go, &ldsB[ring][d0 + 2048]);
  };

  auto body = [&](int ring) {
    const char* bA = (const char*)&ldsA[ring][0];
    const char* bB = (const char*)&ldsB[ring][0];
    bf16x8 a[4], bb[4];
    #pragma unroll
    for (int m = 0; m < 4; m++) a[m] = *(const bf16x8*)(bA + offA[m]);
    #pragma unroll
    for (int n = 0; n < 4; n++) bb[n] = *(const bf16x8*)(bB + offB[n]);
    __builtin_amdgcn_s_setprio(1);
    #pragma unroll
    for (int m = 0; m < 4; m++)
      #pragma unroll
      for (int n = 0; n < 4; n++)
        acc[m][n] = __builtin_amdgcn_mfma_f32_16x16x32_bf16(a[m], bb[n], acc[m][n], 0, 0, 0);
    __builtin_amdgcn_s_setprio(0);
  };

  const int nk = (MODE == 1) ? 32 : (K / 32);
  stage(0); stage(1); stage(2);
  PIPE_FENCE(8);
  #pragma unroll 1
  for (int kt = 0; kt < nk - 3; ++kt) {
    stage(kt + 3);
    body(kt & 3);
    PIPE_FENCE(8);
  }
  body((nk - 3) & 3);
  PIPE_FENCE(4);
  body((nk - 2) & 3);
  PIPE_FENCE(0);
  body((nk - 1) & 3);

  const int rowbase = j0 + wm * 64;
  const int colbase = bn * 128 + wn * 64;
  #pragma unroll
  for (int m = 0; m < 4; m++) {
    #pragma unroll
    for (int n = 0; n < 4; n++) {
      #pragma unroll
      for (int v = 0; v < 4; v++) {
        int r = rowbase + m * 16 + (l >> 4) * 4 + v;
        int cc = colbase + n * 16 + lane15;
        if (r < jend) {
          if (MODE == 1) {
            outU[(size_t)kc * (NTOK * R_DIM) + (size_t)r * R_DIM + cc] = f2bf(acc[m][n][v]);
          } else {
            outU[(size_t)r * O_DIM + cc] = f2bf(2.0f * acc[m][n][v]);
          }
        }
      }
    }
  }
}

// ---------------- reduce bf16 split-K partials -> bf16 H16s ----------------
__global__ void reduce_h(const unsigned short* __restrict__ hp, unsigned short* __restrict__ h16) {
  size_t g = (size_t)blockIdx.x * 256 + threadIdx.x;
  float s[8] = {0,0,0,0,0,0,0,0};
  #pragma unroll
  for (int c = 0; c < KSPLIT; c++) {
    int4 v = ((const int4*)hp)[g + (size_t)c * (NTOK * R_DIM / 8)];
    const unsigned short* us = (const unsigned short*)&v;
    #pragma unroll
    for (int i = 0; i < 8; i++) s[i] += bf2f(us[i]);
  }
  union { unsigned short h[8]; int4 v; } u;
  #pragma unroll
  for (int i = 0; i < 8; i++) u.h[i] = f2bf(s[i]);
  ((int4*)h16)[g] = u.v;
}

// ---------------- workspace layout (bytes) ----------------
#define X16_OFF   ((size_t)0)             // 67108864
#define W16_OFF   ((size_t)67108864)      // 33554432
#define A16T_OFF  ((size_t)100663296)     // 16777216
#define B16T_OFF  ((size_t)117440512)     // 16777216
#define H16S_OFF  ((size_t)134217728)     // 4194304
#define PERM_OFF  ((size_t)138412032)     // 32768
#define INVP_OFF  ((size_t)138444800)     // 32768
#define TILEE_OFF ((size_t)138477568)     // 512
#define TILEJ0_OFF ((size_t)138478080)
#define TILEJE_OFF ((size_t)138478592)
#define NT_OFF    ((size_t)138479104)
#define HP16_OFF  ((size_t)138479616)     // 16777216
#define LOUT_OFF  ((size_t)155256832)     // 67108864

extern "C" void kernel_launch(void* const* d_in, const int* in_sizes, int n_in,
                              void* d_out, int out_size, void* d_ws, size_t ws_size,
                              hipStream_t stream) {
  const float* x  = (const float*)d_in[0];
  const float* wb = (const float*)d_in[1];
  const float* la = (const float*)d_in[2];
  const float* lb = (const float*)d_in[3];
  const int* tok  = (const int*)d_in[4];
  float* out = (float*)d_out;

  char* ws = (char*)d_ws;
  unsigned short* X16  = (unsigned short*)(ws + X16_OFF);
  unsigned short* W16  = (unsigned short*)(ws + W16_OFF);
  unsigned short* A16t = (unsigned short*)(ws + A16T_OFF);
  unsigned short* B16t = (unsigned short*)(ws + B16T_OFF);
  unsigned short* H16s = (unsigned short*)(ws + H16S_OFF);
  unsigned short* HP16 = (unsigned short*)(ws + HP16_OFF);
  unsigned short* LOUT = (unsigned short*)(ws + LOUT_OFF);
  int* perm  = (int*)(ws + PERM_OFF);
  int* invp  = (int*)(ws + INVP_OFF);
  int* tl_e  = (int*)(ws + TILEE_OFF);
  int* tl_j0 = (int*)(ws + TILEJ0_OFF);
  int* tl_je = (int*)(ws + TILEJE_OFF);
  int* nt    = (int*)(ws + NT_OFF);

  prologue<<<40961, 256, 0, stream>>>(x, wb, la, lb, X16, W16, A16t, B16t,
                                      tok, perm, invp, tl_e, tl_j0, tl_je, nt);

  gemm_nt<1><<<dim3(71, 2, KSPLIT), 256, 0, stream>>>(X16, A16t, HP16,
                                                      perm, tl_e, tl_j0, tl_je, nt, D_DIM);
  reduce_h<<<1024, 256, 0, stream>>>(HP16, H16s);
  gemm_nt<3><<<dim3(71, 32), 256, 0, stream>>>(H16s, B16t, LOUT,
                                               perm, tl_e, tl_j0, tl_je, nt, R_DIM);
  gemm256_q<1><<<512, 512, 0, stream>>>(X16, W16, out, LOUT, invp);
}

// Round 14
// 405.140 us; speedup vs baseline: 1.3881x; 1.3035x over previous
//
#include <hip/hip_runtime.h>

// Problem constants
#define S_TOK 4096
#define D_DIM 4096
#define O_DIM 4096
#define R_DIM 256
#define E_EXP 8
#define NTOK  8192   // B*S
#define KSPLIT 4

typedef __bf16 bf16x8 __attribute__((ext_vector_type(8)));
typedef float  f32x4  __attribute__((ext_vector_type(4)));

__device__ __forceinline__ unsigned short f2bf(float f) {
  unsigned int u = __float_as_uint(f);
  u += 0x7FFFu + ((u >> 16) & 1u);   // RNE (no NaN in data)
  return (unsigned short)(u >> 16);
}
__device__ __forceinline__ float bf2f(unsigned short h) {
  return __uint_as_float(((unsigned int)h) << 16);
}

__device__ __forceinline__ void gload_lds16(const unsigned short* g, unsigned short* l) {
  __builtin_amdgcn_global_load_lds((const __attribute__((address_space(1))) void*)g,
                                   (__attribute__((address_space(3))) void*)l, 16, 0, 0);
}

#define PIPE_FENCE(N)                                                        \
  do {                                                                       \
    asm volatile("s_waitcnt vmcnt(" #N ")\n\ts_barrier" ::: "memory");       \
    __builtin_amdgcn_sched_barrier(0);                                       \
  } while (0)
#define BARX                                                                 \
  do {                                                                       \
    asm volatile("s_barrier" ::: "memory");                                  \
    __builtin_amdgcn_sched_barrier(0);                                       \
  } while (0)

// ============ merged prologue: casts + transposes + token sort ============
__global__ void prologue(const float* __restrict__ x, const float* __restrict__ wb,
                         const float* __restrict__ la, const float* __restrict__ lb,
                         unsigned short* __restrict__ X16, unsigned short* __restrict__ W16,
                         unsigned short* __restrict__ A16t, unsigned short* __restrict__ B16t,
                         const int* __restrict__ tt, int* __restrict__ token_perm,
                         int* __restrict__ tile_e, int* __restrict__ tile_j0,
                         int* __restrict__ tile_jend, int* __restrict__ ntiles_out,
                         int* __restrict__ seg_n, int* __restrict__ seg_e,
                         int* __restrict__ seg_lo, int* __restrict__ seg_hi,
                         unsigned short* __restrict__ zp) {
  __shared__ int sm[10256];
  const int b = blockIdx.x, t = threadIdx.x;
  if (b >= 40960) {
    int* ltt   = sm;
    int* lc    = sm + 4096;
    int* ssl   = sm + 6144;
    int* basee = sm + 10240;
    int* cnte  = sm + 10248;
    if (t < 64) ((long long*)zp)[t] = 0;   // 512 B zero page
    for (int s = t; s < S_TOK; s += 256) ltt[s] = tt[s];
    __syncthreads();
    int c[8] = {0,0,0,0,0,0,0,0};
    #pragma unroll
    for (int i = 0; i < 16; i++) { int e = ltt[t * 16 + i]; c[e]++; }
    #pragma unroll
    for (int e = 0; e < 8; e++) lc[t * 8 + e] = c[e];
    __syncthreads();
    if (t < 8) {
      int run = 0;
      for (int qq = 0; qq < 256; qq++) { int tmp = lc[qq * 8 + t]; lc[qq * 8 + t] = run; run += tmp; }
      cnte[t] = run;
    }
    __syncthreads();
    if (t == 0) { int tot = 0; for (int e = 0; e < 8; e++) { basee[e] = tot; tot += cnte[e]; } }
    __syncthreads();
    int off[8];
    #pragma unroll
    for (int e = 0; e < 8; e++) off[e] = basee[e] + lc[t * 8 + e];
    #pragma unroll
    for (int i = 0; i < 16; i++) { int s = t * 16 + i; int e = ltt[s]; ssl[off[e]++] = s; }
    __syncthreads();
    for (int j = t; j < NTOK; j += 256) {
      token_perm[j] = ((j & 1) << 12) + ssl[j >> 1];
    }
    if (t == 0) {
      int nt = 0;
      for (int e = 0; e < 8; e++) {
        int js = 2 * basee[e], je = js + 2 * cnte[e];
        for (int j0 = js; j0 < je; j0 += 128) {
          tile_e[nt] = e; tile_j0[nt] = j0;
          tile_jend[nt] = (je < j0 + 128) ? je : (j0 + 128);
          nt++;
        }
      }
      *ntiles_out = nt;
      // per-256-row-panel expert segments (panel-relative [lo,hi))
      for (int p = 0; p < 32; p++) {
        int plo = p * 256, phi = plo + 256, ns = 0;
        for (int e = 0; e < 8; e++) {
          int es = 2 * basee[e], ee = es + 2 * cnte[e];
          int lo = es > plo ? es : plo;
          int hi = ee < phi ? ee : phi;
          if (lo < hi) { seg_e[p * 8 + ns] = e; seg_lo[p * 8 + ns] = lo - plo;
                         seg_hi[p * 8 + ns] = hi - plo; ns++; }
        }
        seg_n[p] = ns;
      }
    }
    return;
  }
  if (b < 24576) {
    const float* in  = (b < 16384) ? x : wb;
    unsigned short* out = (b < 16384) ? X16 : W16;
    size_t g = (size_t)((b < 16384) ? b : (b - 16384)) * 256 + t;
    const float4* i4 = (const float4*)in;
    float4 a = i4[g * 2], c = i4[g * 2 + 1];
    union { unsigned short h[8]; int4 v; } u;
    u.h[0] = f2bf(a.x); u.h[1] = f2bf(a.y); u.h[2] = f2bf(a.z); u.h[3] = f2bf(a.w);
    u.h[4] = f2bf(c.x); u.h[5] = f2bf(c.y); u.h[6] = f2bf(c.z); u.h[7] = f2bf(c.w);
    ((int4*)out)[g] = u.v;
    return;
  }
  unsigned short (*tile)[33] = (unsigned short (*)[33])sm;
  const float* in; unsigned short* out; int P, Q, pt, qt, e;
  if (b < 32768) {
    int b2 = b - 24576; e = b2 >> 10; int rem = b2 & 1023;
    in = la; out = A16t; P = D_DIM; Q = R_DIM;
    pt = (rem >> 3) * 32; qt = (rem & 7) * 32;
  } else {
    int b3 = b - 32768; e = b3 >> 10; int rem = b3 & 1023;
    in = lb; out = B16t; P = R_DIM; Q = D_DIM;
    pt = (rem & 7) * 32; qt = (rem >> 3) * 32;
  }
  const float* ie = in + (size_t)e * P * Q;
  unsigned short* oe = out + (size_t)e * P * Q;
  int tx = t & 31, ty = t >> 5;
  #pragma unroll
  for (int i = 0; i < 32; i += 8) {
    int p = pt + ty + i, q = qt + tx;
    tile[ty + i][tx] = f2bf(ie[(size_t)p * Q + q]);
  }
  __syncthreads();
  #pragma unroll
  for (int i = 0; i < 32; i += 8) {
    int q = qt + ty + i, p = pt + tx;
    oe[(size_t)q * P + p] = tile[tx][ty + i];
  }
}

// ============ 256x256 dense GEMM over SORTED rows + fused LoRA K-extension ============
// Main loop: byte-identical schedule to the R9/R11-verified skeleton (frozen);
// A rows gathered via perm (sorted), C scatter-written via perm.
// Extension: per expert segment of the panel, 4 K-tiles over H16s (K=256,
// pre-scaled 2x) x B16t[e]; rows outside segment stage from a 512B zero page.
// Conservative sync: vmcnt(0)+barrier per ext K-tile; rings alternate; every
// ds_read is MFMA-consumed before each barrier (WAR-safe).
__global__ __launch_bounds__(512, 2) void gemm256_s(
    const unsigned short* __restrict__ A, const unsigned short* __restrict__ B,
    const unsigned short* __restrict__ H, const unsigned short* __restrict__ Bl,
    float* __restrict__ C, const int* __restrict__ perm,
    const int* __restrict__ seg_n, const int* __restrict__ seg_e,
    const int* __restrict__ seg_lo, const int* __restrict__ seg_hi,
    const unsigned short* __restrict__ zp) {
  __shared__ __align__(16) unsigned short ldsA[2][2][8192];
  __shared__ __align__(16) unsigned short ldsB[2][2][8192];
  int b = blockIdx.x;
  int xc = b & 7, q = b >> 3;
  const int bm = (xc >> 1) * 8 + (q >> 3);   // 0..31
  const int bn = (xc & 1) * 8 + (q & 7);     // 0..15
  const int tid = threadIdx.x, l = tid & 63, w = tid >> 6;
  const int wm = w >> 2, wn = w & 3;

  // staging geometry (per-thread): chunk0 row r0 in [0,128), chunk1 row r1 in [128,256)
  const int i0 = tid, r0 = i0 >> 2;
  const int c0 = ((i0 & 3) * 16) ^ (((r0 >> 1) & 3) << 4);
  const int i1 = 512 + tid, r1 = i1 >> 2;
  const int c1 = ((i1 & 3) * 16) ^ (((r1 >> 1) & 3) << 4);
  const int sr0 = perm[bm * 256 + r0];
  const int sr1 = perm[bm * 256 + r1];
  const unsigned short* srcA0 = A + (size_t)sr0 * 4096 + (c0 >> 1);
  const unsigned short* srcA1 = A + (size_t)sr1 * 4096 + (c1 >> 1);
  const unsigned short* srcB0 = B + (size_t)(bn * 256 + r0) * 4096 + (c0 >> 1);
  const unsigned short* srcB1 = B + (size_t)(bn * 256 + r1) * 4096 + (c1 >> 1);

  const int lane15 = l & 15, kb16 = (l >> 4) * 16;
  int offA[8], offB[4];
  #pragma unroll
  for (int m = 0; m < 8; m++) {
    int r = wm * 128 + m * 16 + lane15;
    offA[m] = r * 64 + (kb16 ^ (((r >> 1) & 3) << 4));
  }
  #pragma unroll
  for (int n = 0; n < 4; n++) {
    int r = wn * 64 + n * 16 + lane15;
    offB[n] = r * 64 + (kb16 ^ (((r >> 1) & 3) << 4));
  }

  f32x4 acc[8][4];
  #pragma unroll
  for (int m = 0; m < 8; m++)
    #pragma unroll
    for (int n = 0; n < 4; n++) acc[m][n] = (f32x4){0.f, 0.f, 0.f, 0.f};

  bf16x8 Ab0[4], Ab1[4], Bb0[4], Bb1[4];

#define STAGE_A(tt, kh) do { int _o = (tt) * 64 + (kh) * 32;                  \
    gload_lds16(srcA0 + _o, &ldsA[(tt) & 1][kh][tid * 8]);                    \
    gload_lds16(srcA1 + _o, &ldsA[(tt) & 1][kh][tid * 8 + 4096]); } while (0)
#define STAGE_B(tt, kh) do { int _o = (tt) * 64 + (kh) * 32;                  \
    gload_lds16(srcB0 + _o, &ldsB[(tt) & 1][kh][tid * 8]);                    \
    gload_lds16(srcB1 + _o, &ldsB[(tt) & 1][kh][tid * 8 + 4096]); } while (0)
#define RD_A(RING, QQ, KS, BUF) do {                                          \
    const char* _s = (const char*)&ldsA[RING][KS][0];                         \
    BUF[0] = *(const bf16x8*)(_s + offA[(QQ) * 4 + 0]);                       \
    BUF[1] = *(const bf16x8*)(_s + offA[(QQ) * 4 + 1]);                       \
    BUF[2] = *(const bf16x8*)(_s + offA[(QQ) * 4 + 2]);                       \
    BUF[3] = *(const bf16x8*)(_s + offA[(QQ) * 4 + 3]); } while (0)
#define RD_B(RING, KS, BUF) do {                                              \
    const char* _s = (const char*)&ldsB[RING][KS][0];                         \
    BUF[0] = *(const bf16x8*)(_s + offB[0]);                                  \
    BUF[1] = *(const bf16x8*)(_s + offB[1]);                                  \
    BUF[2] = *(const bf16x8*)(_s + offB[2]);                                  \
    BUF[3] = *(const bf16x8*)(_s + offB[3]); } while (0)
#define PRIO_MFMA(Q, AB, BB) do {                                             \
    __builtin_amdgcn_s_setprio(1);                                            \
    _Pragma("unroll")                                                         \
    for (int mm = 0; mm < 4; mm++)                                            \
      _Pragma("unroll")                                                       \
      for (int nn = 0; nn < 4; nn++)                                          \
        acc[(Q) * 4 + mm][nn] = __builtin_amdgcn_mfma_f32_16x16x32_bf16(      \
            AB[mm], BB[nn], acc[(Q) * 4 + mm][nn], 0, 0, 0);                  \
    __builtin_amdgcn_s_setprio(0); } while (0)

  // ---- main loop (frozen R9/R11 skeleton) ----
  STAGE_A(0, 0); STAGE_B(0, 0); STAGE_A(0, 1); STAGE_B(0, 1);
  STAGE_A(1, 0); STAGE_B(1, 0);
  PIPE_FENCE(4);
  RD_B(0, 0, Bb0); RD_A(0, 0, 0, Ab0);

  #pragma unroll 1
  for (int t = 0; t < 62; ++t) {
    const int r = t & 1, nr = r ^ 1;
    RD_A(r, 1, 0, Ab1); STAGE_A(t + 1, 1);
    PRIO_MFMA(0, Ab0, Bb0);
    RD_B(r, 1, Bb1); RD_A(r, 0, 1, Ab0); STAGE_B(t + 1, 1);
    PRIO_MFMA(1, Ab1, Bb0);
    PIPE_FENCE(4);
    RD_A(r, 1, 1, Ab1); STAGE_A(t + 2, 0);
    PRIO_MFMA(0, Ab0, Bb1);
    RD_B(nr, 0, Bb0); RD_A(nr, 0, 0, Ab0); STAGE_B(t + 2, 0);
    PRIO_MFMA(1, Ab1, Bb1);
    PIPE_FENCE(4);
  }
  RD_A(0, 1, 0, Ab1); STAGE_A(63, 1); PRIO_MFMA(0, Ab0, Bb0);
  RD_B(0, 1, Bb1); RD_A(0, 0, 1, Ab0); STAGE_B(63, 1); PRIO_MFMA(1, Ab1, Bb0);
  PIPE_FENCE(4);
  RD_A(0, 1, 1, Ab1); PRIO_MFMA(0, Ab0, Bb1);
  RD_B(1, 0, Bb0); RD_A(1, 0, 0, Ab0); PRIO_MFMA(1, Ab1, Bb1);
  PIPE_FENCE(0);
  RD_A(1, 1, 0, Ab1); PRIO_MFMA(0, Ab0, Bb0);
  RD_B(1, 1, Bb1); RD_A(1, 0, 1, Ab0); PRIO_MFMA(1, Ab1, Bb0);
  RD_A(1, 1, 1, Ab1); PRIO_MFMA(0, Ab0, Bb1);
  PRIO_MFMA(1, Ab1, Bb1);

  // ---- LoRA K-extension: acc += (2H)[sorted rows] @ B_e^T per expert segment ----
  const int pn = seg_n[bm];
  #pragma unroll 1
  for (int s = 0; s < pn; ++s) {
    const int eE = seg_e[bm * 8 + s], lo = seg_lo[bm * 8 + s], hi = seg_hi[bm * 8 + s];
    const unsigned short* h0 = (r0 >= lo && r0 < hi)
        ? H + (size_t)(bm * 256 + r0) * 256 + (c0 >> 1) : zp + (c0 >> 1);
    const unsigned short* h1 = (r1 >= lo && r1 < hi)
        ? H + (size_t)(bm * 256 + r1) * 256 + (c1 >> 1) : zp + (c1 >> 1);
    const unsigned short* be0 = Bl + (size_t)eE * (O_DIM * R_DIM)
        + (size_t)(bn * 256 + r0) * 256 + (c0 >> 1);
    const unsigned short* be1 = Bl + (size_t)eE * (O_DIM * R_DIM)
        + (size_t)(bn * 256 + r1) * 256 + (c1 >> 1);
    #pragma unroll 1
    for (int kt = 0; kt < 4; ++kt) {
      const int rg = kt & 1;
      const int o0 = kt * 64, o1 = kt * 64 + 32;
      gload_lds16(h0 + o0,  &ldsA[rg][0][tid * 8]);
      gload_lds16(h1 + o0,  &ldsA[rg][0][tid * 8 + 4096]);
      gload_lds16(h0 + o1,  &ldsA[rg][1][tid * 8]);
      gload_lds16(h1 + o1,  &ldsA[rg][1][tid * 8 + 4096]);
      gload_lds16(be0 + o0, &ldsB[rg][0][tid * 8]);
      gload_lds16(be1 + o0, &ldsB[rg][0][tid * 8 + 4096]);
      gload_lds16(be0 + o1, &ldsB[rg][1][tid * 8]);
      gload_lds16(be1 + o1, &ldsB[rg][1][tid * 8 + 4096]);
      PIPE_FENCE(0);
      RD_B(rg, 0, Bb0); RD_A(rg, 0, 0, Ab0); PRIO_MFMA(0, Ab0, Bb0);
      RD_A(rg, 1, 0, Ab1);                   PRIO_MFMA(1, Ab1, Bb0);
      RD_B(rg, 1, Bb1); RD_A(rg, 0, 1, Ab0); PRIO_MFMA(0, Ab0, Bb1);
      RD_A(rg, 1, 1, Ab1);                   PRIO_MFMA(1, Ab1, Bb1);
      BARX;
    }
  }

#undef STAGE_A
#undef STAGE_B
#undef RD_A
#undef RD_B
#undef PRIO_MFMA

  const int rowbase = bm * 256 + wm * 128;
  const int colbase = bn * 256 + wn * 64;
  #pragma unroll
  for (int m = 0; m < 8; m++)
    #pragma unroll
    for (int v = 0; v < 4; v++) {
      int rrow = rowbase + m * 16 + (l >> 4) * 4 + v;   // sorted index
      int orow = perm[rrow];
      size_t base = (size_t)orow * O_DIM + colbase + lane15;
      C[base]      = acc[m][0][v];
      C[base + 16] = acc[m][1][v];
      C[base + 32] = acc[m][2][v];
      C[base + 48] = acc[m][3][v];
    }
}

// ======= pipelined 128x128 LoRA stage-1 GEMM (R10/R11 structure, passed) =======
// HP16[kc][j][r] = bf16 partial( X[perm[j]] @ A16t[e]^T ), K-chunk kc
__global__ __launch_bounds__(256, 2) void gemm_nt1(
    const unsigned short* __restrict__ Aop, const unsigned short* __restrict__ Bop,
    unsigned short* __restrict__ outU,
    const int* __restrict__ perm, const int* __restrict__ tile_e,
    const int* __restrict__ tile_j0, const int* __restrict__ tile_jend,
    const int* __restrict__ ntiles) {
  const int K = D_DIM;
  int bm = blockIdx.x, bn = blockIdx.y;
  if (bm >= *ntiles) return;
  int e = tile_e[bm], j0 = tile_j0[bm], jend = tile_jend[bm];
  const int kc = blockIdx.z;
  const int t = threadIdx.x, l = t & 63, w = t >> 6;
  const int wm = w >> 1, wn = w & 1;
  __shared__ __align__(16) unsigned short ldsA[4][4096];
  __shared__ __align__(16) unsigned short ldsB[4][4096];

  const unsigned short *sA0, *sA1, *sB0, *sB1;
  {
    int i0 = t, r0 = i0 >> 2;
    int c0 = ((i0 & 3) * 16) ^ (((r0 >> 1) & 3) << 4);
    int i1 = 256 + t, r1 = i1 >> 2;
    int c1 = ((i1 & 3) * 16) ^ (((r1 >> 1) & 3) << 4);
    int ja = j0 + r0; if (ja > jend - 1) ja = jend - 1;
    int jb = j0 + r1; if (jb > jend - 1) jb = jend - 1;
    int g0 = perm[ja], g1 = perm[jb];
    sA0 = Aop + (size_t)g0 * K + kc * 1024 + (c0 >> 1);
    sA1 = Aop + (size_t)g1 * K + kc * 1024 + (c1 >> 1);
    const unsigned short* bp = Bop + (size_t)e * R_DIM * D_DIM;
    sB0 = bp + (size_t)(bn * 128 + r0) * K + kc * 1024 + (c0 >> 1);
    sB1 = bp + (size_t)(bn * 128 + r1) * K + kc * 1024 + (c1 >> 1);
  }
  const int d0 = t * 8;

  const int lane15 = l & 15, kb16 = (l >> 4) * 16;
  int offA[4], offB[4];
  #pragma unroll
  for (int m = 0; m < 4; m++) {
    int r = wm * 64 + m * 16 + lane15;
    offA[m] = r * 64 + (kb16 ^ (((r >> 1) & 3) << 4));
  }
  #pragma unroll
  for (int n = 0; n < 4; n++) {
    int r = wn * 64 + n * 16 + lane15;
    offB[n] = r * 64 + (kb16 ^ (((r >> 1) & 3) << 4));
  }

  f32x4 acc[4][4];
  #pragma unroll
  for (int m = 0; m < 4; m++)
    #pragma unroll
    for (int n = 0; n < 4; n++) acc[m][n] = (f32x4){0.f, 0.f, 0.f, 0.f};

  auto stage = [&](int tt) {
    const int ring = tt & 3;
    const int go = tt * 32;
    gload_lds16(sA0 + go, &ldsA[ring][d0]);
    gload_lds16(sA1 + go, &ldsA[ring][d0 + 2048]);
    gload_lds16(sB0 + go, &ldsB[ring][d0]);
    gload_lds16(sB1 + go, &ldsB[ring][d0 + 2048]);
  };

  auto body = [&](int ring) {
    const char* bA = (const char*)&ldsA[ring][0];
    const char* bB = (const char*)&ldsB[ring][0];
    bf16x8 a[4], bb[4];
    #pragma unroll
    for (int m = 0; m < 4; m++) a[m] = *(const bf16x8*)(bA + offA[m]);
    #pragma unroll
    for (int n = 0; n < 4; n++) bb[n] = *(const bf16x8*)(bB + offB[n]);
    __builtin_amdgcn_s_setprio(1);
    #pragma unroll
    for (int m = 0; m < 4; m++)
      #pragma unroll
      for (int n = 0; n < 4; n++)
        acc[m][n] = __builtin_amdgcn_mfma_f32_16x16x32_bf16(a[m], bb[n], acc[m][n], 0, 0, 0);
    __builtin_amdgcn_s_setprio(0);
  };

  const int nk = 32;
  stage(0); stage(1); stage(2);
  PIPE_FENCE(8);
  #pragma unroll 1
  for (int kt = 0; kt < nk - 3; ++kt) {
    stage(kt + 3);
    body(kt & 3);
    PIPE_FENCE(8);
  }
  body((nk - 3) & 3);
  PIPE_FENCE(4);
  body((nk - 2) & 3);
  PIPE_FENCE(0);
  body((nk - 1) & 3);

  const int rowbase = j0 + wm * 64;
  const int colbase = bn * 128 + wn * 64;
  #pragma unroll
  for (int m = 0; m < 4; m++) {
    #pragma unroll
    for (int n = 0; n < 4; n++) {
      #pragma unroll
      for (int v = 0; v < 4; v++) {
        int r = rowbase + m * 16 + (l >> 4) * 4 + v;
        int cc = colbase + n * 16 + lane15;
        if (r < jend)
          outU[(size_t)kc * (NTOK * R_DIM) + (size_t)r * R_DIM + cc] = f2bf(acc[m][n][v]);
      }
    }
  }
}

// -------- reduce bf16 split-K partials -> bf16 H16s (pre-scaled by 2) --------
__global__ void reduce_h(const unsigned short* __restrict__ hp, unsigned short* __restrict__ h16) {
  size_t g = (size_t)blockIdx.x * 256 + threadIdx.x;
  float s[8] = {0,0,0,0,0,0,0,0};
  #pragma unroll
  for (int c = 0; c < KSPLIT; c++) {
    int4 v = ((const int4*)hp)[g + (size_t)c * (NTOK * R_DIM / 8)];
    const unsigned short* us = (const unsigned short*)&v;
    #pragma unroll
    for (int i = 0; i < 8; i++) s[i] += bf2f(us[i]);
  }
  union { unsigned short h[8]; int4 v; } u;
  #pragma unroll
  for (int i = 0; i < 8; i++) u.h[i] = f2bf(2.0f * s[i]);   // scale here
  ((int4*)h16)[g] = u.v;
}

// ---------------- workspace layout (bytes) ----------------
#define X16_OFF   ((size_t)0)             // 67108864
#define W16_OFF   ((size_t)67108864)      // 33554432
#define A16T_OFF  ((size_t)100663296)     // 16777216
#define B16T_OFF  ((size_t)117440512)     // 16777216
#define H16S_OFF  ((size_t)134217728)     // 4194304
#define PERM_OFF  ((size_t)138412032)     // 32768
#define TILEE_OFF ((size_t)138477568)     // 512
#define TILEJ0_OFF ((size_t)138478080)
#define TILEJE_OFF ((size_t)138478592)
#define NT_OFF    ((size_t)138479104)
#define HP16_OFF  ((size_t)138479616)     // 16777216
#define SEGN_OFF  ((size_t)155256832)     // 128
#define SEGE_OFF  ((size_t)155257344)     // 1024
#define SEGLO_OFF ((size_t)155258368)     // 1024
#define SEGHI_OFF ((size_t)155259392)     // 1024
#define ZERO_OFF  ((size_t)155260416)     // 512

extern "C" void kernel_launch(void* const* d_in, const int* in_sizes, int n_in,
                              void* d_out, int out_size, void* d_ws, size_t ws_size,
                              hipStream_t stream) {
  const float* x  = (const float*)d_in[0];
  const float* wb = (const float*)d_in[1];
  const float* la = (const float*)d_in[2];
  const float* lb = (const float*)d_in[3];
  const int* tok  = (const int*)d_in[4];
  float* out = (float*)d_out;

  char* ws = (char*)d_ws;
  unsigned short* X16  = (unsigned short*)(ws + X16_OFF);
  unsigned short* W16  = (unsigned short*)(ws + W16_OFF);
  unsigned short* A16t = (unsigned short*)(ws + A16T_OFF);
  unsigned short* B16t = (unsigned short*)(ws + B16T_OFF);
  unsigned short* H16s = (unsigned short*)(ws + H16S_OFF);
  unsigned short* HP16 = (unsigned short*)(ws + HP16_OFF);
  unsigned short* ZP   = (unsigned short*)(ws + ZERO_OFF);
  int* perm  = (int*)(ws + PERM_OFF);
  int* tl_e  = (int*)(ws + TILEE_OFF);
  int* tl_j0 = (int*)(ws + TILEJ0_OFF);
  int* tl_je = (int*)(ws + TILEJE_OFF);
  int* nt    = (int*)(ws + NT_OFF);
  int* sgn   = (int*)(ws + SEGN_OFF);
  int* sge   = (int*)(ws + SEGE_OFF);
  int* sglo  = (int*)(ws + SEGLO_OFF);
  int* sghi  = (int*)(ws + SEGHI_OFF);

  prologue<<<40961, 256, 0, stream>>>(x, wb, la, lb, X16, W16, A16t, B16t,
                                      tok, perm, tl_e, tl_j0, tl_je, nt,
                                      sgn, sge, sglo, sghi, ZP);

  gemm_nt1<<<dim3(71, 2, KSPLIT), 256, 0, stream>>>(X16, A16t, HP16,
                                                    perm, tl_e, tl_j0, tl_je, nt);
  reduce_h<<<1024, 256, 0, stream>>>(HP16, H16s);

  gemm256_s<<<512, 512, 0, stream>>>(X16, W16, H16s, B16t, out, perm,
                                     sgn, sge, sglo, sghi, ZP);
}